// Round 8
// baseline (337.490 us; speedup 1.0000x reference)
//
#include <hip/hip_runtime.h>
#include <hip/hip_bf16.h>
#include <math.h>

#define B_   2
#define S_   2048
#define HID_ 2048
#define NH_  16
#define NKV_ 4
#define HD_  128
#define NTOK (B_*S_)   // 4096

typedef __attribute__((ext_vector_type(8))) short s8v;            // 8 bf16 (MFMA A/B frag)
typedef __attribute__((ext_vector_type(8))) unsigned short u16x8;
typedef __attribute__((ext_vector_type(4))) float f32x4;

__device__ __forceinline__ float fexp2(float x) { return __builtin_amdgcn_exp2f(x); }

__device__ __forceinline__ unsigned short f2bf(float f) {
    unsigned int x = __builtin_bit_cast(unsigned int, f);
    x += 0x7fffu + ((x >> 16) & 1u);           // RNE
    return (unsigned short)(x >> 16);
}
__device__ __forceinline__ float bf2f(unsigned short h) {
    unsigned int x = ((unsigned int)h) << 16;
    return __builtin_bit_cast(float, x);
}

// async global->LDS, 16B per lane; LDS dest = wave-uniform base + lane*16
__device__ __forceinline__ void gload_lds16(const void* g, void* l) {
    __builtin_amdgcn_global_load_lds(
        (__attribute__((address_space(1))) void*)g,
        (__attribute__((address_space(3))) void*)l, 16, 0, 0);
}

// ---------------- all fp32 -> bf16 conversions in ONE kernel --------------------
// ranges: hs (split), w_q (plain), w_k (split), w_v (split), w_o (plain)
__global__ __launch_bounds__(256) void conv_all(
    const float* __restrict__ hs, const float* __restrict__ wq,
    const float* __restrict__ wk, const float* __restrict__ wvp,
    const float* __restrict__ wo,
    unsigned short* __restrict__ hid_h, unsigned short* __restrict__ hid_l,
    unsigned short* __restrict__ wq_h,
    unsigned short* __restrict__ wk_h, unsigned short* __restrict__ wk_l,
    unsigned short* __restrict__ wv_h, unsigned short* __restrict__ wv_l,
    unsigned short* __restrict__ wo_h)
{
    const int nHS = NTOK*HID_/8, nWQ = NH_*HD_*HID_/8, nWK = NKV_*HD_*HID_/8;
    int i = blockIdx.x * 256 + threadIdx.x;
    const float* src; unsigned short* dh; unsigned short* dl = nullptr; int off;
    if (i < nHS)                       { src = hs;  dh = hid_h; dl = hid_l; off = i; }
    else if (i < nHS+nWQ)              { src = wq;  dh = wq_h;  off = i-nHS; }
    else if (i < nHS+nWQ+nWK)          { src = wk;  dh = wk_h;  dl = wk_l; off = i-nHS-nWQ; }
    else if (i < nHS+nWQ+2*nWK)        { src = wvp; dh = wv_h;  dl = wv_l; off = i-nHS-nWQ-nWK; }
    else if (i < nHS+nWQ+2*nWK+nWQ)    { src = wo;  dh = wo_h;  off = i-nHS-nWQ-2*nWK; }
    else return;
    const float4* p = (const float4*)src + (size_t)off * 2;
    float4 a = p[0], b = p[1];
    float x[8] = {a.x,a.y,a.z,a.w,b.x,b.y,b.z,b.w};
    u16x8 oh, ol;
    #pragma unroll
    for (int j=0;j<8;j++) {
        unsigned short h = f2bf(x[j]);
        oh[j] = h;
        ol[j] = f2bf(x[j] - bf2f(h));
    }
    *((u16x8*)dh + off) = oh;
    if (dl) *((u16x8*)dl + off) = ol;
}

// ---------------- fp64-exact RoPE cos/sin table [S][64] -------------------------
__global__ __launch_bounds__(256) void rope_table(float* __restrict__ ctab,
                                                  float* __restrict__ stab) {
    int i = blockIdx.x * 256 + threadIdx.x;      // pos*64 + d
    if (i >= S_*64) return;
    int d = i & 63, pos = i >> 6;
    double inv = pow(1.0e6, -(double)d / 64.0);
    double ang = (double)pos * inv;
    ctab[i] = (float)cos(ang);
    stab[i] = (float)sin(ang);
}

// ---------------- bf16 GEMM with fused epilogues --------------------------------
// C = A @ W^T (+bias). Wave covers full 128-col tile width: NW=4 -> 2x8 frags/wave
// (32 rows), NW=8 -> 1x8 (16 rows). So each output row's 128 cols are lane-local
// per 16-lane group -> RoPE pairs (d,d+64) same lane; quant groups need only a
// 16-lane shfl reduce.
// SPLIT3: 3-pass split-bf16. FUSED: two weight sets (K,V) stacked along N.
// EPI: 0 = fp32 C (+bias). 1 = Q: bias+RoPE+log2e/sqrt(D) scale -> bf16.
//      2 = KV: bias (+RoPE if K) + int4 group quant-dequant -> bf16.
template<int NW, bool SPLIT3, bool FUSED, int EPI>
__global__ __launch_bounds__(NW*64) void gemm_mp(
    const unsigned short* __restrict__ Ah,
    const unsigned short* __restrict__ Al,
    const unsigned short* __restrict__ Bh,
    const unsigned short* __restrict__ Bl,
    const unsigned short* __restrict__ Bh2,
    const unsigned short* __restrict__ Bl2,
    const float* __restrict__ bias,
    const float* __restrict__ bias2,
    float* __restrict__ C,
    unsigned short* __restrict__ Cb,
    unsigned short* __restrict__ Cb2,
    const float* __restrict__ ctab,
    const float* __restrict__ stab,
    int M, int N, int K)
{
    constexpr int ITILES = 128 / (NW*16);   // row frags per wave
    constexpr int RW = 128 / NW;            // rows per wave
    constexpr int CH = 8 / NW;              // staging chunks per wave
    __shared__ unsigned short lsAh[128*32];
    __shared__ unsigned short lsAl[SPLIT3 ? 128*32 : 8];
    __shared__ unsigned short lsBh[128*32];
    __shared__ unsigned short lsBl[SPLIT3 ? 128*32 : 8];
    int tid = threadIdx.x;
    int lane = tid & 63;
    int l15 = lane & 15;
    int wv = tid >> 6;
    int nTiles = N >> 7;
    int tTiles = FUSED ? (nTiles << 1) : nTiles;
    int m0 = (blockIdx.x / tTiles) << 7;
    int nt = blockIdx.x % tTiles;
    bool kbranch = true;
    if (FUSED && nt >= nTiles) { kbranch = false; Bh = Bh2; Bl = Bl2; bias = bias2; Cb = Cb2; nt -= nTiles; }
    int n0 = nt << 7;

    f32x4 acc[ITILES][8];
    for (int i=0;i<ITILES;i++) for (int j=0;j<8;j++) acc[i][j] = (f32x4)0.0f;

    int koff = (lane >> 4) << 3;

    for (int k0 = 0; k0 < K; k0 += 32) {
        #pragma unroll
        for (int j=0; j<CH; j++) {
            int chunk = wv*CH + j;
            int e = chunk*512 + lane*8;          // linear elem index in [128][32] tile
            int r = e >> 5, c = e & 31;
            int ldsoff = chunk*512;
            gload_lds16(Ah + (size_t)(m0 + r)*K + k0 + c, &lsAh[ldsoff]);
            gload_lds16(Bh + (size_t)(n0 + r)*K + k0 + c, &lsBh[ldsoff]);
            if constexpr (SPLIT3) {
                gload_lds16(Al + (size_t)(m0 + r)*K + k0 + c, &lsAl[ldsoff]);
                gload_lds16(Bl + (size_t)(n0 + r)*K + k0 + c, &lsBl[ldsoff]);
            }
        }
        __syncthreads();
        s8v afh[ITILES], afl[ITILES], bfh[8], bfl[8];
        #pragma unroll
        for (int i=0;i<ITILES;i++) {
            int ar = wv*RW + i*16 + l15;
            afh[i] = *(const s8v*)&lsAh[ar*32 + koff];
            if constexpr (SPLIT3) afl[i] = *(const s8v*)&lsAl[ar*32 + koff];
        }
        #pragma unroll
        for (int j=0;j<8;j++) {
            int br = j*16 + l15;
            bfh[j] = *(const s8v*)&lsBh[br*32 + koff];
            if constexpr (SPLIT3) bfl[j] = *(const s8v*)&lsBl[br*32 + koff];
        }
        #pragma unroll
        for (int i=0;i<ITILES;i++)
            #pragma unroll
            for (int j=0;j<8;j++) {
                acc[i][j] = __builtin_amdgcn_mfma_f32_16x16x32_bf16(afh[i], bfh[j], acc[i][j], 0,0,0);
                if constexpr (SPLIT3) {
                    acc[i][j] = __builtin_amdgcn_mfma_f32_16x16x32_bf16(afh[i], bfl[j], acc[i][j], 0,0,0);
                    acc[i][j] = __builtin_amdgcn_mfma_f32_16x16x32_bf16(afl[i], bfh[j], acc[i][j], 0,0,0);
                }
            }
        __syncthreads();
    }

    // ---- epilogue ----
    float bb[8];
    #pragma unroll
    for (int j=0;j<8;j++) bb[j] = (EPI==0 && !bias) ? 0.0f : bias[n0 + j*16 + l15];
    #pragma unroll
    for (int i=0;i<ITILES;i++) {
        #pragma unroll
        for (int r=0;r<4;r++) {
            int row = m0 + wv*RW + i*16 + ((lane>>4)<<2) + r;
            if constexpr (EPI == 0) {
                #pragma unroll
                for (int j=0;j<8;j++)
                    C[(size_t)row*N + n0 + j*16 + l15] = acc[i][j][r] + bb[j];
            } else {
                float y[8];
                #pragma unroll
                for (int j=0;j<8;j++) y[j] = acc[i][j][r] + bb[j];
                if (EPI == 1 || kbranch) {           // RoPE (Q always; K branch of KV)
                    int pos = row & (S_-1);
                    #pragma unroll
                    for (int j=0;j<4;j++) {
                        int dm = j*16 + l15;
                        float cs = ctab[pos*64 + dm];
                        float sn = stab[pos*64 + dm];
                        float x1 = y[j], x2 = y[j+4];
                        y[j]   = x1*cs - x2*sn;
                        y[j+4] = x2*cs + x1*sn;
                    }
                }
                if constexpr (EPI == 1) {
                    const float sc = 0.1275174306f;   // log2(e)/sqrt(128)
                    #pragma unroll
                    for (int j=0;j<8;j++)
                        Cb[(size_t)row*N + n0 + j*16 + l15] = f2bf(y[j] * sc);
                } else {
                    // int4 group quant-dequant: group0 = d 0..63 (j 0..3), group1 = d 64..127
                    float mn0 = fminf(fminf(y[0],y[1]), fminf(y[2],y[3]));
                    float mx0 = fmaxf(fmaxf(y[0],y[1]), fmaxf(y[2],y[3]));
                    float mn1 = fminf(fminf(y[4],y[5]), fminf(y[6],y[7]));
                    float mx1 = fmaxf(fmaxf(y[4],y[5]), fmaxf(y[6],y[7]));
                    #pragma unroll
                    for (int off=1; off<16; off<<=1) {
                        mn0 = fminf(mn0, __shfl_xor(mn0, off));
                        mx0 = fmaxf(mx0, __shfl_xor(mx0, off));
                        mn1 = fminf(mn1, __shfl_xor(mn1, off));
                        mx1 = fmaxf(mx1, __shfl_xor(mx1, off));
                    }
                    float s0 = (mx0 - mn0) / 15.0f; if (s0 == 0.0f) s0 = 1.0f;
                    float s1 = (mx1 - mn1) / 15.0f; if (s1 == 0.0f) s1 = 1.0f;
                    #pragma unroll
                    for (int j=0;j<4;j++) {
                        float q0 = rintf(fminf(fmaxf((y[j]  -mn0)/s0, 0.0f), 15.0f));
                        float q1 = rintf(fminf(fmaxf((y[j+4]-mn1)/s1, 0.0f), 15.0f));
                        Cb[(size_t)row*N + n0 + j*16     + l15] = f2bf(q0*s0 + mn0);
                        Cb[(size_t)row*N + n0 + (j+4)*16 + l15] = f2bf(q1*s1 + mn1);
                    }
                }
            }
        }
    }
}

// ---------------- causal GQA flash attention, bf16 MFMA -------------------------
// 8 waves, QBLK=128; grid 512 blocks, heavy qblk first (dispatch-order tail fix).
// LDS 52KB/block (lsK single, lsV SINGLE, lsP) -> up to 3 blocks/CU.
// Phase graph (2 barriers/tile): QK reads lsK | bar1 | issue loads(t+1), stageK(t+1)
// | softmax | PV reads lsV | bar2 | writeV(t+1) -> lsV. Row-sum via ones-MFMA.
__device__ __forceinline__ int vswz(int d) { return ((d ^ (d >> 3)) & 7) << 4; }
__device__ __forceinline__ int poff(int row) { return row*72 + ((row>>2)<<4); }

__global__ __launch_bounds__(512) void attn_kernel(
    const unsigned short* __restrict__ Qb,   // [NTOK][NH*HD], pre-scaled (log2e/sqrt(D))
    const unsigned short* __restrict__ Kb,   // [NTOK][NKV*HD]
    const unsigned short* __restrict__ Vb,
    unsigned short* __restrict__ Ob)         // [NTOK][NH*HD]
{
    __shared__ unsigned short lsK[64*128];    // [kv][d-chunks], slot c8' holds chunk c8'^(r&7)
    __shared__ unsigned short lsV[128*64];    // [d][kv], elem kv at (kv ^ (sw(d)<<3)) — SINGLE buf
    __shared__ unsigned short lsP[8][1200];   // per-wave P, bank-spread rows (poff)

    int tid = threadIdx.x, lane = tid & 63, wv = tid >> 6;
    int bidx  = blockIdx.x;
    int bh    = bidx & 31;
    int grp   = bidx >> 5;                     // 0..15
    int qblk  = (grp < 8) ? (15 - grp) : (grp - 8);   // heavy blocks dispatch first
    int h     = bh & 15;
    int b     = bh >> 4;
    int hk    = h >> 2;
    size_t tokbase = (size_t)b * S_;
    int prow0 = ((lane>>4)<<2);

    auto stageK = [&](int t) {
        #pragma unroll
        for (int it=0; it<2; it++) {
            int mI = it*8 + wv;
            int r  = mI*4 + (lane>>4);
            int c8 = (lane & 15) ^ (r & 7);
            gload_lds16(Kb + ((tokbase + t*64 + r)*NKV_ + hk)*HD_ + (c8<<3), &lsK[mI*512]);
        }
    };
    auto loadV = [&](int t, uint4* vr) {
        #pragma unroll
        for (int it=0; it<2; it++) {
            int idx2 = it*8 + wv;
            int kvchunk = idx2 & 7, dhalf = idx2 >> 3;
            int e = lane & 7, g = lane >> 3;
            vr[it] = *(const uint4*)(Vb +
                ((tokbase + t*64 + kvchunk*8 + e)*NKV_ + hk)*HD_ + dhalf*64 + g*8);
        }
    };
    auto writeV = [&](uint4* vr) {
        #pragma unroll
        for (int it=0; it<2; it++) {
            int idx2 = it*8 + wv;
            int kvchunk = idx2 & 7, dhalf = idx2 >> 3;
            int e = lane & 7, g = lane >> 3;
            uint4 w = vr[it];
            {   // step 4: 2-dword block swap
                unsigned int s0 = (e&4) ? w.x : w.z;
                unsigned int s1 = (e&4) ? w.y : w.w;
                unsigned int r0 = __shfl_xor(s0, 4);
                unsigned int r1 = __shfl_xor(s1, 4);
                if (e&4) { w.x = r0; w.y = r1; } else { w.z = r0; w.w = r1; }
            }
            {   // step 2: dword-level swap
                unsigned int s0 = (e&2) ? w.x : w.y;
                unsigned int s1 = (e&2) ? w.z : w.w;
                unsigned int r0 = __shfl_xor(s0, 2);
                unsigned int r1 = __shfl_xor(s1, 2);
                if (e&2) { w.x = r0; w.z = r1; } else { w.y = r0; w.w = r1; }
            }
            {   // step 1: u16-within-dword swap
                unsigned int r0 = __shfl_xor(w.x, 1);
                unsigned int r1 = __shfl_xor(w.y, 1);
                unsigned int r2 = __shfl_xor(w.z, 1);
                unsigned int r3 = __shfl_xor(w.w, 1);
                if (e&1) {
                    w.x = (w.x & 0xFFFF0000u) | (r0 >> 16);
                    w.y = (w.y & 0xFFFF0000u) | (r1 >> 16);
                    w.z = (w.z & 0xFFFF0000u) | (r2 >> 16);
                    w.w = (w.w & 0xFFFF0000u) | (r3 >> 16);
                } else {
                    w.x = (w.x & 0x0000FFFFu) | (r0 << 16);
                    w.y = (w.y & 0x0000FFFFu) | (r1 << 16);
                    w.z = (w.z & 0x0000FFFFu) | (r2 << 16);
                    w.w = (w.w & 0x0000FFFFu) | (r3 << 16);
                }
            }
            int d = dhalf*64 + g*8 + e;
            int sw = (d ^ (d>>3)) & 7;
            int kvx = (kvchunk*8) ^ (sw<<3);
            *(uint4*)(&lsV[d*64 + kvx]) = w;
        }
    };

    int q0 = qblk*128 + wv*16;

    s8v qf[4];
    {
        int qrow = q0 + (lane & 15);
        const unsigned short* qp = Qb + ((tokbase + qrow)*NH_ + h)*HD_ + ((lane>>4)<<3);
        #pragma unroll
        for (int kc=0; kc<4; kc++) qf[kc] = *(const s8v*)(qp + kc*32);
    }
    s8v onesf;
    #pragma unroll
    for (int j=0;j<8;j++) onesf[j] = (short)0x3F80;   // bf16 1.0

    f32x4 o[8];
    #pragma unroll
    for (int i=0;i<8;i++) o[i] = (f32x4)0.0f;
    float m[4], l[4];
    #pragma unroll
    for (int r=0;r<4;r++){ m[r] = -INFINITY; l[r] = 0.0f; }

    int qrow_lane = q0 + prow0;
    int nt_end = 2*qblk + 2;

    uint4 vr[2];
    loadV(0, vr);                 // loads first (oldest in vm queue)
    stageK(0);                    // gll after
    writeV(vr);
    __syncthreads();              // drains gll: lsK/lsV ready

    for (int t=0; t<nt_end; t++) {
        bool more = (t+1 < nt_end);                // block-uniform
        bool fullmask = (q0 + 15) < t*64;          // wave-uniform: tile fully masked
        bool needmask = (t*64 + 63) > q0;          // wave-uniform: diagonal region

        // ---- scores: S = Q(16x128) @ K^T(128x64), log2 domain ----
        f32x4 s[4];
        if (!fullmask) {
            __builtin_amdgcn_s_setprio(1);
            #pragma unroll
            for (int nt=0; nt<4; nt++) {
                s[nt] = (f32x4)0.0f;
                int row = nt*16 + (lane & 15);
                #pragma unroll
                for (int kc=0; kc<4; kc++) {
                    int byt = (kc*64 + ((lane>>4)<<4)) ^ ((row & 7) << 4);
                    s8v kfrag = *(const s8v*)&lsK[row*128 + (byt >> 1)];
                    s[nt] = __builtin_amdgcn_mfma_f32_16x16x32_bf16(qf[kc], kfrag, s[nt], 0,0,0);
                }
            }
            __builtin_amdgcn_s_setprio(0);
        }
        if (more) {
            __syncthreads();       // bar1: all QK reads of lsK done
            loadV(t+1, vr);        // issue next V loads (regs)
            stageK(t+1);           // issue next K gll into lsK
        }
        if (!fullmask) {
            // ---- causal mask (diagonal tiles only) + online softmax (exp2) ----
            float mt[4];
            #pragma unroll
            for (int r=0;r<4;r++) mt[r] = -INFINITY;
            if (needmask) {
                int kvb = t*64 + (lane & 15);
                #pragma unroll
                for (int nt=0; nt<4; nt++) {
                    int kvg = kvb + nt*16;
                    #pragma unroll
                    for (int r=0;r<4;r++) {
                        float sv = s[nt][r];
                        if (kvg > qrow_lane + r) sv = -1e30f;
                        s[nt][r] = sv;
                        mt[r] = fmaxf(mt[r], sv);
                    }
                }
            } else {
                #pragma unroll
                for (int nt=0; nt<4; nt++)
                    #pragma unroll
                    for (int r=0;r<4;r++) mt[r] = fmaxf(mt[r], s[nt][r]);
            }
            #pragma unroll
            for (int r=0;r<4;r++) {
                #pragma unroll
                for (int off=1; off<16; off<<=1) mt[r] = fmaxf(mt[r], __shfl_xor(mt[r], off));
            }
            // defer-max (T13): skip rescale if wave-wide growth <= 8 (values <= 2^8)
            float dm = fmaxf(fmaxf(mt[0]-m[0], mt[1]-m[1]), fmaxf(mt[2]-m[2], mt[3]-m[3]));
            bool rescale = !__all(dm <= 8.0f);
            if (rescale) {
                float scl[4];
                #pragma unroll
                for (int r=0;r<4;r++) {
                    float mn = fmaxf(m[r], mt[r]);
                    scl[r] = fexp2(m[r] - mn);     // m=-inf first tile -> 0
                    m[r] = mn;
                    l[r] *= scl[r];
                }
                #pragma unroll
                for (int dt=0; dt<8; dt++)
                    #pragma unroll
                    for (int r=0;r<4;r++) o[dt][r] *= scl[r];
            }
            #pragma unroll
            for (int nt=0; nt<4; nt++) {
                int col = nt*16 + (lane & 15);
                #pragma unroll
                for (int r=0;r<4;r++) {
                    float pv = fexp2(s[nt][r] - m[r]);
                    lsP[wv][poff(prow0 + r) + col] = f2bf(pv);
                }
            }
            // ---- PV: O += P(16x64) @ V(64x128); row-sum l via ones-MFMA ----
            s8v pa[2];
            #pragma unroll
            for (int c=0;c<2;c++)
                pa[c] = *(const s8v*)&lsP[wv][poff(lane & 15) + ((lane>>4)<<3) + c*32];
            __builtin_amdgcn_s_setprio(1);
            f32x4 ls = __builtin_amdgcn_mfma_f32_16x16x32_bf16(pa[0], onesf, (f32x4)0.0f, 0,0,0);
            ls = __builtin_amdgcn_mfma_f32_16x16x32_bf16(pa[1], onesf, ls, 0,0,0);
            #pragma unroll
            for (int dt=0; dt<8; dt++) {
                int row = dt*16 + (lane & 15);
                #pragma unroll
                for (int c=0;c<2;c++) {
                    int byt = (c*64 + ((lane>>4)<<4)) ^ vswz(row);
                    s8v vfrag = *(const s8v*)&lsV[row*64 + (byt >> 1)];
                    o[dt] = __builtin_amdgcn_mfma_f32_16x16x32_bf16(pa[c], vfrag, o[dt], 0,0,0);
                }
            }
            __builtin_amdgcn_s_setprio(0);
            #pragma unroll
            for (int r=0;r<4;r++) l[r] += ls[r];
        }
        __syncthreads();           // bar2: all PV reads of lsV done; gll drained
        if (more) writeV(vr);      // publish V(t+1) into lsV (visible at next bar1)
    }
    // ---- epilogue ----
    #pragma unroll
    for (int dt=0; dt<8; dt++) {
        #pragma unroll
        for (int r=0;r<4;r++) {
            int rq = q0 + prow0 + r;
            int d  = dt*16 + (lane & 15);
            float val = o[dt][r] / l[r];
            Ob[((tokbase + rq)*NH_ + h)*HD_ + d] = f2bf(val);
        }
    }
}

// ---------------- host launcher --------------------------------------------------
extern "C" void kernel_launch(void* const* d_in, const int* in_sizes, int n_in,
                              void* d_out, int out_size, void* d_ws, size_t ws_size,
                              hipStream_t stream) {
    const float* hs  = (const float*)d_in[0];
    const float* w_q = (const float*)d_in[1];
    const float* b_q = (const float*)d_in[2];
    const float* w_k = (const float*)d_in[3];
    const float* b_k = (const float*)d_in[4];
    const float* w_v = (const float*)d_in[5];
    const float* b_v = (const float*)d_in[6];
    const float* w_o = (const float*)d_in[7];
    float* out = (float*)d_out;

    char* p = (char*)d_ws;
    auto alloc = [&](size_t bytes) { char* r = p; p += (bytes + 255) & ~(size_t)255; return r; };
    unsigned short* hid_h = (unsigned short*)alloc((size_t)NTOK*HID_*2);
    unsigned short* hid_l = (unsigned short*)alloc((size_t)NTOK*HID_*2);
    unsigned short* wq_h  = (unsigned short*)alloc((size_t)NH_*HD_*HID_*2);
    unsigned short* wk_h  = (unsigned short*)alloc((size_t)NKV_*HD_*HID_*2);
    unsigned short* wk_l  = (unsigned short*)alloc((size_t)NKV_*HD_*HID_*2);
    unsigned short* wv_h  = (unsigned short*)alloc((size_t)NKV_*HD_*HID_*2);
    unsigned short* wv_l  = (unsigned short*)alloc((size_t)NKV_*HD_*HID_*2);
    unsigned short* wo_h  = (unsigned short*)alloc((size_t)HID_*NH_*HD_*2);
    unsigned short* qb = (unsigned short*)alloc((size_t)NTOK*NH_*HD_*2);
    unsigned short* kb = (unsigned short*)alloc((size_t)NTOK*NKV_*HD_*2);
    unsigned short* vb = (unsigned short*)alloc((size_t)NTOK*NKV_*HD_*2);
    unsigned short* ao = (unsigned short*)alloc((size_t)NTOK*NH_*HD_*2);
    float* ctab = (float*)alloc((size_t)S_*64*4);
    float* stab = (float*)alloc((size_t)S_*64*4);

    // all fp32 -> bf16 conversions (1 launch)
    {
        int n8 = NTOK*HID_/8 + NH_*HD_*HID_/8 + 2*(NKV_*HD_*HID_/8) + HID_*NH_*HD_/8;
        conv_all<<<(n8 + 255)/256, 256, 0, stream>>>(
            hs, w_q, w_k, w_v, w_o, hid_h, hid_l, wq_h, wk_h, wk_l, wv_h, wv_l, wo_h);
    }
    rope_table<<<(S_*64 + 255)/256, 256, 0, stream>>>(ctab, stab);

    // Q projection + fused RoPE + scale -> qb bf16 (1-pass, NW=4, grid 512)
    gemm_mp<4,false,false,1><<<(NTOK/128)*(HID_/128), 256, 0, stream>>>(
        hid_h, nullptr, wq_h, nullptr, nullptr, nullptr, b_q, nullptr,
        nullptr, qb, nullptr, ctab, stab, NTOK, NH_*HD_, HID_);

    // K+V projections (fused along N, 3-pass split) + fused RoPE(K)+quant -> kb/vb
    gemm_mp<8,true,true,2><<<(NTOK/128)*2*((NKV_*HD_)/128), 512, 0, stream>>>(
        hid_h, hid_l, wk_h, wk_l, wv_h, wv_l, b_k, b_v,
        nullptr, kb, vb, ctab, stab, NTOK, NKV_*HD_, HID_);

    // causal GQA attention: 512 blocks x 8 waves, QBLK=128, heavy-first, ~52KB LDS
    attn_kernel<<<B_*NH_*16, 512, 0, stream>>>(qb, kb, vb, ao);

    // output projection (no bias), 1-pass bf16 -> fp32 d_out
    gemm_mp<4,false,false,0><<<(NTOK/128)*(HID_/128), 256, 0, stream>>>(
        ao, nullptr, wo_h, nullptr, nullptr, nullptr, nullptr, nullptr,
        out, nullptr, nullptr, nullptr, nullptr, NTOK, HID_, HID_);
}

// Round 9
// 328.556 us; speedup vs baseline: 1.0272x; 1.0272x over previous
//
#include <hip/hip_runtime.h>
#include <hip/hip_bf16.h>
#include <math.h>

#define B_   2
#define S_   2048
#define HID_ 2048
#define NH_  16
#define NKV_ 4
#define HD_  128
#define NTOK (B_*S_)   // 4096

typedef __attribute__((ext_vector_type(8))) short s8v;            // 8 bf16 (MFMA A/B frag)
typedef __attribute__((ext_vector_type(8))) unsigned short u16x8;
typedef __attribute__((ext_vector_type(4))) float f32x4;
typedef __attribute__((ext_vector_type(4))) unsigned int u32x4;

__device__ __forceinline__ float fexp2(float x) { return __builtin_amdgcn_exp2f(x); }

__device__ __forceinline__ unsigned short f2bf(float f) {
    unsigned int x = __builtin_bit_cast(unsigned int, f);
    x += 0x7fffu + ((x >> 16) & 1u);           // RNE
    return (unsigned short)(x >> 16);
}
__device__ __forceinline__ float bf2f(unsigned short h) {
    unsigned int x = ((unsigned int)h) << 16;
    return __builtin_bit_cast(float, x);
}

// async global->LDS, 16B per lane; LDS dest = wave-uniform base + lane*16
__device__ __forceinline__ void gload_lds16(const void* g, void* l) {
    __builtin_amdgcn_global_load_lds(
        (__attribute__((address_space(1))) void*)g,
        (__attribute__((address_space(3))) void*)l, 16, 0, 0);
}

// ---------------- all fp32 -> bf16 conversions in ONE kernel --------------------
__global__ __launch_bounds__(256) void conv_all(
    const float* __restrict__ hs, const float* __restrict__ wq,
    const float* __restrict__ wk, const float* __restrict__ wvp,
    const float* __restrict__ wo,
    unsigned short* __restrict__ hid_h, unsigned short* __restrict__ hid_l,
    unsigned short* __restrict__ wq_h,
    unsigned short* __restrict__ wk_h, unsigned short* __restrict__ wk_l,
    unsigned short* __restrict__ wv_h, unsigned short* __restrict__ wv_l,
    unsigned short* __restrict__ wo_h)
{
    const int nHS = NTOK*HID_/8, nWQ = NH_*HD_*HID_/8, nWK = NKV_*HD_*HID_/8;
    int i = blockIdx.x * 256 + threadIdx.x;
    const float* src; unsigned short* dh; unsigned short* dl = nullptr; int off;
    if (i < nHS)                       { src = hs;  dh = hid_h; dl = hid_l; off = i; }
    else if (i < nHS+nWQ)              { src = wq;  dh = wq_h;  off = i-nHS; }
    else if (i < nHS+nWQ+nWK)          { src = wk;  dh = wk_h;  dl = wk_l; off = i-nHS-nWQ; }
    else if (i < nHS+nWQ+2*nWK)        { src = wvp; dh = wv_h;  dl = wv_l; off = i-nHS-nWQ-nWK; }
    else if (i < nHS+nWQ+2*nWK+nWQ)    { src = wo;  dh = wo_h;  off = i-nHS-nWQ-2*nWK; }
    else return;
    const float4* p = (const float4*)src + (size_t)off * 2;
    float4 a = p[0], b = p[1];
    float x[8] = {a.x,a.y,a.z,a.w,b.x,b.y,b.z,b.w};
    u16x8 oh, ol;
    #pragma unroll
    for (int j=0;j<8;j++) {
        unsigned short h = f2bf(x[j]);
        oh[j] = h;
        ol[j] = f2bf(x[j] - bf2f(h));
    }
    *((u16x8*)dh + off) = oh;
    if (dl) *((u16x8*)dl + off) = ol;
}

// ---------------- fp64-exact RoPE cos/sin table [S][64] -------------------------
__global__ __launch_bounds__(256) void rope_table(float* __restrict__ ctab,
                                                  float* __restrict__ stab) {
    int i = blockIdx.x * 256 + threadIdx.x;      // pos*64 + d
    if (i >= S_*64) return;
    int d = i & 63, pos = i >> 6;
    double inv = pow(1.0e6, -(double)d / 64.0);
    double ang = (double)pos * inv;
    ctab[i] = (float)cos(ang);
    stab[i] = (float)sin(ang);
}

// ---------------- bf16 GEMM with fused epilogues --------------------------------
// (unchanged from R7 — proven)
template<int NW, bool SPLIT3, bool FUSED, int EPI>
__global__ __launch_bounds__(NW*64) void gemm_mp(
    const unsigned short* __restrict__ Ah,
    const unsigned short* __restrict__ Al,
    const unsigned short* __restrict__ Bh,
    const unsigned short* __restrict__ Bl,
    const unsigned short* __restrict__ Bh2,
    const unsigned short* __restrict__ Bl2,
    const float* __restrict__ bias,
    const float* __restrict__ bias2,
    float* __restrict__ C,
    unsigned short* __restrict__ Cb,
    unsigned short* __restrict__ Cb2,
    const float* __restrict__ ctab,
    const float* __restrict__ stab,
    int M, int N, int K)
{
    constexpr int ITILES = 128 / (NW*16);   // row frags per wave
    constexpr int RW = 128 / NW;            // rows per wave
    constexpr int CH = 8 / NW;              // staging chunks per wave
    __shared__ unsigned short lsAh[128*32];
    __shared__ unsigned short lsAl[SPLIT3 ? 128*32 : 8];
    __shared__ unsigned short lsBh[128*32];
    __shared__ unsigned short lsBl[SPLIT3 ? 128*32 : 8];
    int tid = threadIdx.x;
    int lane = tid & 63;
    int l15 = lane & 15;
    int wv = tid >> 6;
    int nTiles = N >> 7;
    int tTiles = FUSED ? (nTiles << 1) : nTiles;
    int m0 = (blockIdx.x / tTiles) << 7;
    int nt = blockIdx.x % tTiles;
    bool kbranch = true;
    if (FUSED && nt >= nTiles) { kbranch = false; Bh = Bh2; Bl = Bl2; bias = bias2; Cb = Cb2; nt -= nTiles; }
    int n0 = nt << 7;

    f32x4 acc[ITILES][8];
    for (int i=0;i<ITILES;i++) for (int j=0;j<8;j++) acc[i][j] = (f32x4)0.0f;

    int koff = (lane >> 4) << 3;

    for (int k0 = 0; k0 < K; k0 += 32) {
        #pragma unroll
        for (int j=0; j<CH; j++) {
            int chunk = wv*CH + j;
            int e = chunk*512 + lane*8;          // linear elem index in [128][32] tile
            int r = e >> 5, c = e & 31;
            int ldsoff = chunk*512;
            gload_lds16(Ah + (size_t)(m0 + r)*K + k0 + c, &lsAh[ldsoff]);
            gload_lds16(Bh + (size_t)(n0 + r)*K + k0 + c, &lsBh[ldsoff]);
            if constexpr (SPLIT3) {
                gload_lds16(Al + (size_t)(m0 + r)*K + k0 + c, &lsAl[ldsoff]);
                gload_lds16(Bl + (size_t)(n0 + r)*K + k0 + c, &lsBl[ldsoff]);
            }
        }
        __syncthreads();
        s8v afh[ITILES], afl[ITILES], bfh[8], bfl[8];
        #pragma unroll
        for (int i=0;i<ITILES;i++) {
            int ar = wv*RW + i*16 + l15;
            afh[i] = *(const s8v*)&lsAh[ar*32 + koff];
            if constexpr (SPLIT3) afl[i] = *(const s8v*)&lsAl[ar*32 + koff];
        }
        #pragma unroll
        for (int j=0;j<8;j++) {
            int br = j*16 + l15;
            bfh[j] = *(const s8v*)&lsBh[br*32 + koff];
            if constexpr (SPLIT3) bfl[j] = *(const s8v*)&lsBl[br*32 + koff];
        }
        #pragma unroll
        for (int i=0;i<ITILES;i++)
            #pragma unroll
            for (int j=0;j<8;j++) {
                acc[i][j] = __builtin_amdgcn_mfma_f32_16x16x32_bf16(afh[i], bfh[j], acc[i][j], 0,0,0);
                if constexpr (SPLIT3) {
                    acc[i][j] = __builtin_amdgcn_mfma_f32_16x16x32_bf16(afh[i], bfl[j], acc[i][j], 0,0,0);
                    acc[i][j] = __builtin_amdgcn_mfma_f32_16x16x32_bf16(afl[i], bfh[j], acc[i][j], 0,0,0);
                }
            }
        __syncthreads();
    }

    // ---- epilogue ----
    float bb[8];
    #pragma unroll
    for (int j=0;j<8;j++) bb[j] = (EPI==0 && !bias) ? 0.0f : bias[n0 + j*16 + l15];
    #pragma unroll
    for (int i=0;i<ITILES;i++) {
        #pragma unroll
        for (int r=0;r<4;r++) {
            int row = m0 + wv*RW + i*16 + ((lane>>4)<<2) + r;
            if constexpr (EPI == 0) {
                #pragma unroll
                for (int j=0;j<8;j++)
                    C[(size_t)row*N + n0 + j*16 + l15] = acc[i][j][r] + bb[j];
            } else {
                float y[8];
                #pragma unroll
                for (int j=0;j<8;j++) y[j] = acc[i][j][r] + bb[j];
                if (EPI == 1 || kbranch) {           // RoPE (Q always; K branch of KV)
                    int pos = row & (S_-1);
                    #pragma unroll
                    for (int j=0;j<4;j++) {
                        int dm = j*16 + l15;
                        float cs = ctab[pos*64 + dm];
                        float sn = stab[pos*64 + dm];
                        float x1 = y[j], x2 = y[j+4];
                        y[j]   = x1*cs - x2*sn;
                        y[j+4] = x2*cs + x1*sn;
                    }
                }
                if constexpr (EPI == 1) {
                    const float sc = 0.1275174306f;   // log2(e)/sqrt(128)
                    #pragma unroll
                    for (int j=0;j<8;j++)
                        Cb[(size_t)row*N + n0 + j*16 + l15] = f2bf(y[j] * sc);
                } else {
                    // int4 group quant-dequant: group0 = d 0..63, group1 = d 64..127
                    float mn0 = fminf(fminf(y[0],y[1]), fminf(y[2],y[3]));
                    float mx0 = fmaxf(fmaxf(y[0],y[1]), fmaxf(y[2],y[3]));
                    float mn1 = fminf(fminf(y[4],y[5]), fminf(y[6],y[7]));
                    float mx1 = fmaxf(fmaxf(y[4],y[5]), fmaxf(y[6],y[7]));
                    #pragma unroll
                    for (int off=1; off<16; off<<=1) {
                        mn0 = fminf(mn0, __shfl_xor(mn0, off));
                        mx0 = fmaxf(mx0, __shfl_xor(mx0, off));
                        mn1 = fminf(mn1, __shfl_xor(mn1, off));
                        mx1 = fmaxf(mx1, __shfl_xor(mx1, off));
                    }
                    float s0 = (mx0 - mn0) / 15.0f; if (s0 == 0.0f) s0 = 1.0f;
                    float s1 = (mx1 - mn1) / 15.0f; if (s1 == 0.0f) s1 = 1.0f;
                    #pragma unroll
                    for (int j=0;j<4;j++) {
                        float q0 = rintf(fminf(fmaxf((y[j]  -mn0)/s0, 0.0f), 15.0f));
                        float q1 = rintf(fminf(fmaxf((y[j+4]-mn1)/s1, 0.0f), 15.0f));
                        Cb[(size_t)row*N + n0 + j*16     + l15] = f2bf(q0*s0 + mn0);
                        Cb[(size_t)row*N + n0 + (j+4)*16 + l15] = f2bf(q1*s1 + mn1);
                    }
                }
            }
        }
    }
}

// ---------------- causal GQA flash attention, swapped-QK^T ----------------------
// 8 waves, QBLK=128; grid 512 blocks, heavy qblk dispatched first.
// Swapped scores: S^T = mfma(K, Q) -> lane holds ONE q row (q0 + lane&15),
// kv = t*64 + nt*16 + 4*(lane>>4) + r. Softmax: local + 2 shfl_xor. P A-frags
// formed IN-REGISTER (cvt_pk + 16 bpermute) -> NO lsP. LDS = 48 KB (<64KB).
// K single-buffer gll; V double-buffer reg-transpose (R7 pipeline, proven).
__device__ __forceinline__ int vswz(int d) { return ((d ^ (d >> 3)) & 7) << 4; }

__global__ __launch_bounds__(512) void attn_kernel(
    const unsigned short* __restrict__ Qb,   // [NTOK][NH*HD], pre-scaled (log2e/sqrt(D))
    const unsigned short* __restrict__ Kb,   // [NTOK][NKV*HD]
    const unsigned short* __restrict__ Vb,
    unsigned short* __restrict__ Ob)         // [NTOK][NH*HD]
{
    __shared__ unsigned short lsK[64*128];    // [kv][d-chunks], slot c8' holds chunk c8'^(r&7)
    __shared__ unsigned short lsV[2][128*64]; // [d][kv], elem kv at (kv ^ (sw(d)<<3))

    int tid = threadIdx.x, lane = tid & 63, wv = tid >> 6;
    int bidx  = blockIdx.x;
    int bh    = bidx & 31;
    int grp   = bidx >> 5;                     // 0..15
    int qblk  = (grp < 8) ? (15 - grp) : (grp - 8);   // heavy blocks dispatch first
    int h     = bh & 15;
    int b     = bh >> 4;
    int hk    = h >> 2;
    size_t tokbase = (size_t)b * S_;
    int l15 = lane & 15;
    int g   = lane >> 4;
    int prow0 = g << 2;

    auto stageK = [&](int t) {
        #pragma unroll
        for (int it=0; it<2; it++) {
            int mI = it*8 + wv;
            int r  = mI*4 + (lane>>4);
            int c8 = (lane & 15) ^ (r & 7);
            gload_lds16(Kb + ((tokbase + t*64 + r)*NKV_ + hk)*HD_ + (c8<<3), &lsK[mI*512]);
        }
    };
    auto loadV = [&](int t, uint4* vr) {
        #pragma unroll
        for (int it=0; it<2; it++) {
            int idx2 = it*8 + wv;
            int kvchunk = idx2 & 7, dhalf = idx2 >> 3;
            int e = lane & 7, gg = lane >> 3;
            vr[it] = *(const uint4*)(Vb +
                ((tokbase + t*64 + kvchunk*8 + e)*NKV_ + hk)*HD_ + dhalf*64 + gg*8);
        }
    };
    auto writeV = [&](uint4* vr, unsigned short* dstV) {
        #pragma unroll
        for (int it=0; it<2; it++) {
            int idx2 = it*8 + wv;
            int kvchunk = idx2 & 7, dhalf = idx2 >> 3;
            int e = lane & 7, gg = lane >> 3;
            uint4 w = vr[it];
            {   // step 4: 2-dword block swap
                unsigned int s0 = (e&4) ? w.x : w.z;
                unsigned int s1 = (e&4) ? w.y : w.w;
                unsigned int r0 = __shfl_xor(s0, 4);
                unsigned int r1 = __shfl_xor(s1, 4);
                if (e&4) { w.x = r0; w.y = r1; } else { w.z = r0; w.w = r1; }
            }
            {   // step 2: dword-level swap
                unsigned int s0 = (e&2) ? w.x : w.y;
                unsigned int s1 = (e&2) ? w.z : w.w;
                unsigned int r0 = __shfl_xor(s0, 2);
                unsigned int r1 = __shfl_xor(s1, 2);
                if (e&2) { w.x = r0; w.z = r1; } else { w.y = r0; w.w = r1; }
            }
            {   // step 1: u16-within-dword swap
                unsigned int r0 = __shfl_xor(w.x, 1);
                unsigned int r1 = __shfl_xor(w.y, 1);
                unsigned int r2 = __shfl_xor(w.z, 1);
                unsigned int r3 = __shfl_xor(w.w, 1);
                if (e&1) {
                    w.x = (w.x & 0xFFFF0000u) | (r0 >> 16);
                    w.y = (w.y & 0xFFFF0000u) | (r1 >> 16);
                    w.z = (w.z & 0xFFFF0000u) | (r2 >> 16);
                    w.w = (w.w & 0xFFFF0000u) | (r3 >> 16);
                } else {
                    w.x = (w.x & 0x0000FFFFu) | (r0 << 16);
                    w.y = (w.y & 0x0000FFFFu) | (r1 << 16);
                    w.z = (w.z & 0x0000FFFFu) | (r2 << 16);
                    w.w = (w.w & 0x0000FFFFu) | (r3 << 16);
                }
            }
            int d = dhalf*64 + gg*8 + e;
            int sw = (d ^ (d>>3)) & 7;
            int kvx = (kvchunk*8) ^ (sw<<3);
            *(uint4*)(dstV + d*64 + kvx) = w;
        }
    };

    int q0 = qblk*128 + wv*16;
    int qlane = q0 + l15;                      // this lane's q row (swapped layout)

    s8v qf[4];
    {
        int qrow = q0 + l15;
        const unsigned short* qp = Qb + ((tokbase + qrow)*NH_ + h)*HD_ + (g<<3);
        #pragma unroll
        for (int kc=0; kc<4; kc++) qf[kc] = *(const s8v*)(qp + kc*32);
    }

    f32x4 o[8];
    #pragma unroll
    for (int i=0;i<8;i++) o[i] = (f32x4)0.0f;
    float m = -INFINITY, l = 0.0f;             // per-lane (one q row)

    int nt_end = 2*qblk + 2;

    uint4 vr[2];
    loadV(0, vr);                 // loads first (oldest in vm queue)
    stageK(0);                    // gll after -> writeV wait leaves it in flight
    writeV(vr, &lsV[0][0]);
    __syncthreads();              // drains gll: lsK/lsV[0] ready

    for (int t=0; t<nt_end; t++) {
        int cur = t & 1;
        bool more = (t+1 < nt_end);                // block-uniform
        bool fullmask = (q0 + 15) < t*64;          // wave-uniform: tile fully masked
        bool needmask = (t*64 + 63) > q0;          // wave-uniform: diagonal region

        // ---- scores (swapped): S^T = K(64x128) @ Q^T -> lane q = qlane ----
        f32x4 s[4];
        if (!fullmask) {
            __builtin_amdgcn_s_setprio(1);
            #pragma unroll
            for (int nt=0; nt<4; nt++) {
                s[nt] = (f32x4)0.0f;
                int row = nt*16 + l15;
                #pragma unroll
                for (int kc=0; kc<4; kc++) {
                    int byt = (kc*64 + (g<<4)) ^ ((row & 7) << 4);
                    s8v kfrag = *(const s8v*)&lsK[row*128 + (byt >> 1)];
                    s[nt] = __builtin_amdgcn_mfma_f32_16x16x32_bf16(kfrag, qf[kc], s[nt], 0,0,0);
                }
            }
            __builtin_amdgcn_s_setprio(0);
        }
        if (more) {
            __syncthreads();       // bar1: all QK reads of lsK done (vm queue empty)
            loadV(t+1, vr);        // issue next V loads (regs)
            stageK(t+1);           // issue next K gll into lsK
        }
        s8v pa[2];
        if (!fullmask) {
            // ---- causal mask + online softmax (exp2), per-lane scalar state ----
            float mt = -INFINITY;
            if (needmask) {
                #pragma unroll
                for (int nt=0; nt<4; nt++)
                    #pragma unroll
                    for (int r=0;r<4;r++) {
                        int kvg = t*64 + nt*16 + (g<<2) + r;
                        float sv = s[nt][r];
                        if (kvg > qlane) sv = -1e30f;
                        s[nt][r] = sv;
                        mt = fmaxf(mt, sv);
                    }
            } else {
                #pragma unroll
                for (int nt=0; nt<4; nt++)
                    #pragma unroll
                    for (int r=0;r<4;r++) mt = fmaxf(mt, s[nt][r]);
            }
            mt = fmaxf(mt, __shfl_xor(mt, 16));
            mt = fmaxf(mt, __shfl_xor(mt, 32));
            // defer-max (T13): skip rescale if growth <= 8 (values <= 2^8)
            bool rescale = !__all(mt - m <= 8.0f);
            if (rescale) {
                float mn = fmaxf(m, mt);
                float scl = fexp2(m - mn);     // m=-inf first tile -> 0
                m = mn;
                l *= scl;
                #pragma unroll
                for (int r=0;r<4;r++) {
                    float sr = __shfl(scl, (prow0 + r) + (lane & 48));
                    #pragma unroll
                    for (int dt=0; dt<8; dt++) o[dt][r] *= sr;
                }
            }
            float p[4][4];
            float rs = 0.0f;
            #pragma unroll
            for (int nt=0; nt<4; nt++)
                #pragma unroll
                for (int r=0;r<4;r++) {
                    p[nt][r] = fexp2(s[nt][r] - m);
                    rs += p[nt][r];
                }
            rs += __shfl_xor(rs, 16);
            rs += __shfl_xor(rs, 32);
            l += rs;
            // ---- in-register P -> A-frag (cvt_pk + bpermute); no LDS ----
            unsigned int wpk[4][2];
            #pragma unroll
            for (int nt=0; nt<4; nt++)
                #pragma unroll
                for (int pr=0; pr<2; pr++) {
                    unsigned int w_;
                    asm("v_cvt_pk_bf16_f32 %0, %1, %2"
                        : "=v"(w_) : "v"(p[nt][2*pr]), "v"(p[nt][2*pr+1]));
                    wpk[nt][pr] = w_;
                }
            #pragma unroll
            for (int c=0;c<2;c++) {
                unsigned int dw[4];
                #pragma unroll
                for (int i=0;i<4;i++) {
                    int srcl = l15 + 16*(2*(g&1) + (i>>1));
                    unsigned int a0 = (unsigned int)__shfl((int)wpk[2*c+0][i&1], srcl);
                    unsigned int a1 = (unsigned int)__shfl((int)wpk[2*c+1][i&1], srcl);
                    dw[i] = (g>>1) ? a1 : a0;
                }
                uint4 t4; t4.x = dw[0]; t4.y = dw[1]; t4.z = dw[2]; t4.w = dw[3];
                pa[c] = __builtin_bit_cast(s8v, t4);
            }
        }
        if (more) writeV(vr, &lsV[cur^1][0]);   // waits only V loads (gll in flight)
        if (!fullmask) {
            // ---- PV: O += P(16x64) @ V(64x128) ----
            __builtin_amdgcn_s_setprio(1);
            #pragma unroll
            for (int dt=0; dt<8; dt++) {
                int row = dt*16 + l15;
                #pragma unroll
                for (int c=0;c<2;c++) {
                    int byt = (c*64 + (g<<4)) ^ vswz(row);
                    s8v vfrag = *(const s8v*)&lsV[cur][row*64 + (byt >> 1)];
                    o[dt] = __builtin_amdgcn_mfma_f32_16x16x32_bf16(pa[c], vfrag, o[dt], 0,0,0);
                }
            }
            __builtin_amdgcn_s_setprio(0);
        }
        __syncthreads();           // bar2: drains gll; publishes lsK(t+1), lsV[cur^1]
    }
    // ---- epilogue: redistribute per-q l across lane groups ----
    #pragma unroll
    for (int r=0;r<4;r++) {
        float lr = __shfl(l, (prow0 + r) + (lane & 48));
        float inv = 1.0f / lr;
        int rq = q0 + prow0 + r;
        #pragma unroll
        for (int dt=0; dt<8; dt++) {
            int d = dt*16 + l15;
            Ob[((tokbase + rq)*NH_ + h)*HD_ + d] = f2bf(o[dt][r] * inv);
        }
    }
}

// ---------------- host launcher --------------------------------------------------
extern "C" void kernel_launch(void* const* d_in, const int* in_sizes, int n_in,
                              void* d_out, int out_size, void* d_ws, size_t ws_size,
                              hipStream_t stream) {
    const float* hs  = (const float*)d_in[0];
    const float* w_q = (const float*)d_in[1];
    const float* b_q = (const float*)d_in[2];
    const float* w_k = (const float*)d_in[3];
    const float* b_k = (const float*)d_in[4];
    const float* w_v = (const float*)d_in[5];
    const float* b_v = (const float*)d_in[6];
    const float* w_o = (const float*)d_in[7];
    float* out = (float*)d_out;

    char* p = (char*)d_ws;
    auto alloc = [&](size_t bytes) { char* r = p; p += (bytes + 255) & ~(size_t)255; return r; };
    unsigned short* hid_h = (unsigned short*)alloc((size_t)NTOK*HID_*2);
    unsigned short* hid_l = (unsigned short*)alloc((size_t)NTOK*HID_*2);
    unsigned short* wq_h  = (unsigned short*)alloc((size_t)NH_*HD_*HID_*2);
    unsigned short* wk_h  = (unsigned short*)alloc((size_t)NKV_*HD_*HID_*2);
    unsigned short* wk_l  = (unsigned short*)alloc((size_t)NKV_*HD_*HID_*2);
    unsigned short* wv_h  = (unsigned short*)alloc((size_t)NKV_*HD_*HID_*2);
    unsigned short* wv_l  = (unsigned short*)alloc((size_t)NKV_*HD_*HID_*2);
    unsigned short* wo_h  = (unsigned short*)alloc((size_t)HID_*NH_*HD_*2);
    unsigned short* qb = (unsigned short*)alloc((size_t)NTOK*NH_*HD_*2);
    unsigned short* kb = (unsigned short*)alloc((size_t)NTOK*NKV_*HD_*2);
    unsigned short* vb = (unsigned short*)alloc((size_t)NTOK*NKV_*HD_*2);
    unsigned short* ao = (unsigned short*)alloc((size_t)NTOK*NH_*HD_*2);
    float* ctab = (float*)alloc((size_t)S_*64*4);
    float* stab = (float*)alloc((size_t)S_*64*4);

    // all fp32 -> bf16 conversions (1 launch)
    {
        int n8 = NTOK*HID_/8 + NH_*HD_*HID_/8 + 2*(NKV_*HD_*HID_/8) + HID_*NH_*HD_/8;
        conv_all<<<(n8 + 255)/256, 256, 0, stream>>>(
            hs, w_q, w_k, w_v, w_o, hid_h, hid_l, wq_h, wk_h, wk_l, wv_h, wv_l, wo_h);
    }
    rope_table<<<(S_*64 + 255)/256, 256, 0, stream>>>(ctab, stab);

    // Q projection + fused RoPE + scale -> qb bf16 (1-pass, NW=4)
    gemm_mp<4,false,false,1><<<(NTOK/128)*(HID_/128), 256, 0, stream>>>(
        hid_h, nullptr, wq_h, nullptr, nullptr, nullptr, b_q, nullptr,
        nullptr, qb, nullptr, ctab, stab, NTOK, NH_*HD_, HID_);

    // K+V projections (fused along N, 3-pass split) + fused RoPE(K)+quant -> kb/vb
    gemm_mp<8,true,true,2><<<(NTOK/128)*2*((NKV_*HD_)/128), 512, 0, stream>>>(
        hid_h, hid_l, wk_h, wk_l, wv_h, wv_l, b_k, b_v,
        nullptr, kb, vb, ctab, stab, NTOK, NKV_*HD_, HID_);

    // causal GQA attention: 512 blocks x 8 waves, QBLK=128, 48KB LDS, heavy-first
    attn_kernel<<<B_*NH_*16, 512, 0, stream>>>(qb, kb, vb, ao);

    // output projection (no bias), 1-pass bf16 -> fp32 d_out
    gemm_mp<4,false,false,0><<<(NTOK/128)*(HID_/128), 256, 0, stream>>>(
        ao, nullptr, wo_h, nullptr, nullptr, nullptr, nullptr, nullptr,
        out, nullptr, nullptr, nullptr, nullptr, NTOK, HID_, HID_);
}

// Round 10
// 320.284 us; speedup vs baseline: 1.0537x; 1.0258x over previous
//
#include <hip/hip_runtime.h>
#include <hip/hip_bf16.h>
#include <math.h>

#define B_   2
#define S_   2048
#define HID_ 2048
#define NH_  16
#define NKV_ 4
#define HD_  128
#define NTOK (B_*S_)   // 4096

typedef __attribute__((ext_vector_type(8))) short s8v;            // 8 bf16 (MFMA A/B frag)
typedef __attribute__((ext_vector_type(8))) unsigned short u16x8;
typedef __attribute__((ext_vector_type(4))) float f32x4;

__device__ __forceinline__ float fexp2(float x) { return __builtin_amdgcn_exp2f(x); }

__device__ __forceinline__ unsigned short f2bf(float f) {
    unsigned int x = __builtin_bit_cast(unsigned int, f);
    x += 0x7fffu + ((x >> 16) & 1u);           // RNE
    return (unsigned short)(x >> 16);
}
__device__ __forceinline__ float bf2f(unsigned short h) {
    unsigned int x = ((unsigned int)h) << 16;
    return __builtin_bit_cast(float, x);
}

// async global->LDS, 16B per lane; LDS dest = wave-uniform base + lane*16
__device__ __forceinline__ void gload_lds16(const void* g, void* l) {
    __builtin_amdgcn_global_load_lds(
        (__attribute__((address_space(1))) void*)g,
        (__attribute__((address_space(3))) void*)l, 16, 0, 0);
}

// ---------------- all fp32 -> bf16 conversions in ONE kernel --------------------
__global__ __launch_bounds__(256) void conv_all(
    const float* __restrict__ hs, const float* __restrict__ wq,
    const float* __restrict__ wk, const float* __restrict__ wvp,
    const float* __restrict__ wo,
    unsigned short* __restrict__ hid_h, unsigned short* __restrict__ hid_l,
    unsigned short* __restrict__ wq_h,
    unsigned short* __restrict__ wk_h, unsigned short* __restrict__ wk_l,
    unsigned short* __restrict__ wv_h, unsigned short* __restrict__ wv_l,
    unsigned short* __restrict__ wo_h)
{
    const int nHS = NTOK*HID_/8, nWQ = NH_*HD_*HID_/8, nWK = NKV_*HD_*HID_/8;
    int i = blockIdx.x * 256 + threadIdx.x;
    const float* src; unsigned short* dh; unsigned short* dl = nullptr; int off;
    if (i < nHS)                       { src = hs;  dh = hid_h; dl = hid_l; off = i; }
    else if (i < nHS+nWQ)              { src = wq;  dh = wq_h;  off = i-nHS; }
    else if (i < nHS+nWQ+nWK)          { src = wk;  dh = wk_h;  dl = wk_l; off = i-nHS-nWQ; }
    else if (i < nHS+nWQ+2*nWK)        { src = wvp; dh = wv_h;  dl = wv_l; off = i-nHS-nWQ-nWK; }
    else if (i < nHS+nWQ+2*nWK+nWQ)    { src = wo;  dh = wo_h;  off = i-nHS-nWQ-2*nWK; }
    else return;
    const float4* p = (const float4*)src + (size_t)off * 2;
    float4 a = p[0], b = p[1];
    float x[8] = {a.x,a.y,a.z,a.w,b.x,b.y,b.z,b.w};
    u16x8 oh, ol;
    #pragma unroll
    for (int j=0;j<8;j++) {
        unsigned short h = f2bf(x[j]);
        oh[j] = h;
        ol[j] = f2bf(x[j] - bf2f(h));
    }
    *((u16x8*)dh + off) = oh;
    if (dl) *((u16x8*)dl + off) = ol;
}

// ---------------- fp64-exact RoPE cos/sin table [S][64] -------------------------
__global__ __launch_bounds__(256) void rope_table(float* __restrict__ ctab,
                                                  float* __restrict__ stab) {
    int i = blockIdx.x * 256 + threadIdx.x;      // pos*64 + d
    if (i >= S_*64) return;
    int d = i & 63, pos = i >> 6;
    double inv = pow(1.0e6, -(double)d / 64.0);
    double ang = (double)pos * inv;
    ctab[i] = (float)cos(ang);
    stab[i] = (float)sin(ang);
}

// ---------------- bf16 GEMM with fused epilogues --------------------------------
// (unchanged from R7 — proven)
template<int NW, bool SPLIT3, bool FUSED, int EPI>
__global__ __launch_bounds__(NW*64) void gemm_mp(
    const unsigned short* __restrict__ Ah,
    const unsigned short* __restrict__ Al,
    const unsigned short* __restrict__ Bh,
    const unsigned short* __restrict__ Bl,
    const unsigned short* __restrict__ Bh2,
    const unsigned short* __restrict__ Bl2,
    const float* __restrict__ bias,
    const float* __restrict__ bias2,
    float* __restrict__ C,
    unsigned short* __restrict__ Cb,
    unsigned short* __restrict__ Cb2,
    const float* __restrict__ ctab,
    const float* __restrict__ stab,
    int M, int N, int K)
{
    constexpr int ITILES = 128 / (NW*16);   // row frags per wave
    constexpr int RW = 128 / NW;            // rows per wave
    constexpr int CH = 8 / NW;              // staging chunks per wave
    __shared__ unsigned short lsAh[128*32];
    __shared__ unsigned short lsAl[SPLIT3 ? 128*32 : 8];
    __shared__ unsigned short lsBh[128*32];
    __shared__ unsigned short lsBl[SPLIT3 ? 128*32 : 8];
    int tid = threadIdx.x;
    int lane = tid & 63;
    int l15 = lane & 15;
    int wv = tid >> 6;
    int nTiles = N >> 7;
    int tTiles = FUSED ? (nTiles << 1) : nTiles;
    int m0 = (blockIdx.x / tTiles) << 7;
    int nt = blockIdx.x % tTiles;
    bool kbranch = true;
    if (FUSED && nt >= nTiles) { kbranch = false; Bh = Bh2; Bl = Bl2; bias = bias2; Cb = Cb2; nt -= nTiles; }
    int n0 = nt << 7;

    f32x4 acc[ITILES][8];
    for (int i=0;i<ITILES;i++) for (int j=0;j<8;j++) acc[i][j] = (f32x4)0.0f;

    int koff = (lane >> 4) << 3;

    for (int k0 = 0; k0 < K; k0 += 32) {
        #pragma unroll
        for (int j=0; j<CH; j++) {
            int chunk = wv*CH + j;
            int e = chunk*512 + lane*8;          // linear elem index in [128][32] tile
            int r = e >> 5, c = e & 31;
            int ldsoff = chunk*512;
            gload_lds16(Ah + (size_t)(m0 + r)*K + k0 + c, &lsAh[ldsoff]);
            gload_lds16(Bh + (size_t)(n0 + r)*K + k0 + c, &lsBh[ldsoff]);
            if constexpr (SPLIT3) {
                gload_lds16(Al + (size_t)(m0 + r)*K + k0 + c, &lsAl[ldsoff]);
                gload_lds16(Bl + (size_t)(n0 + r)*K + k0 + c, &lsBl[ldsoff]);
            }
        }
        __syncthreads();
        s8v afh[ITILES], afl[ITILES], bfh[8], bfl[8];
        #pragma unroll
        for (int i=0;i<ITILES;i++) {
            int ar = wv*RW + i*16 + l15;
            afh[i] = *(const s8v*)&lsAh[ar*32 + koff];
            if constexpr (SPLIT3) afl[i] = *(const s8v*)&lsAl[ar*32 + koff];
        }
        #pragma unroll
        for (int j=0;j<8;j++) {
            int br = j*16 + l15;
            bfh[j] = *(const s8v*)&lsBh[br*32 + koff];
            if constexpr (SPLIT3) bfl[j] = *(const s8v*)&lsBl[br*32 + koff];
        }
        #pragma unroll
        for (int i=0;i<ITILES;i++)
            #pragma unroll
            for (int j=0;j<8;j++) {
                acc[i][j] = __builtin_amdgcn_mfma_f32_16x16x32_bf16(afh[i], bfh[j], acc[i][j], 0,0,0);
                if constexpr (SPLIT3) {
                    acc[i][j] = __builtin_amdgcn_mfma_f32_16x16x32_bf16(afh[i], bfl[j], acc[i][j], 0,0,0);
                    acc[i][j] = __builtin_amdgcn_mfma_f32_16x16x32_bf16(afl[i], bfh[j], acc[i][j], 0,0,0);
                }
            }
        __syncthreads();
    }

    // ---- epilogue ----
    float bb[8];
    #pragma unroll
    for (int j=0;j<8;j++) bb[j] = (EPI==0 && !bias) ? 0.0f : bias[n0 + j*16 + l15];
    #pragma unroll
    for (int i=0;i<ITILES;i++) {
        #pragma unroll
        for (int r=0;r<4;r++) {
            int row = m0 + wv*RW + i*16 + ((lane>>4)<<2) + r;
            if constexpr (EPI == 0) {
                #pragma unroll
                for (int j=0;j<8;j++)
                    C[(size_t)row*N + n0 + j*16 + l15] = acc[i][j][r] + bb[j];
            } else {
                float y[8];
                #pragma unroll
                for (int j=0;j<8;j++) y[j] = acc[i][j][r] + bb[j];
                if (EPI == 1 || kbranch) {           // RoPE (Q always; K branch of KV)
                    int pos = row & (S_-1);
                    #pragma unroll
                    for (int j=0;j<4;j++) {
                        int dm = j*16 + l15;
                        float cs = ctab[pos*64 + dm];
                        float sn = stab[pos*64 + dm];
                        float x1 = y[j], x2 = y[j+4];
                        y[j]   = x1*cs - x2*sn;
                        y[j+4] = x2*cs + x1*sn;
                    }
                }
                if constexpr (EPI == 1) {
                    const float sc = 0.1275174306f;   // log2(e)/sqrt(128)
                    #pragma unroll
                    for (int j=0;j<8;j++)
                        Cb[(size_t)row*N + n0 + j*16 + l15] = f2bf(y[j] * sc);
                } else {
                    // int4 group quant-dequant: group0 = d 0..63, group1 = d 64..127
                    float mn0 = fminf(fminf(y[0],y[1]), fminf(y[2],y[3]));
                    float mx0 = fmaxf(fmaxf(y[0],y[1]), fmaxf(y[2],y[3]));
                    float mn1 = fminf(fminf(y[4],y[5]), fminf(y[6],y[7]));
                    float mx1 = fmaxf(fmaxf(y[4],y[5]), fmaxf(y[6],y[7]));
                    #pragma unroll
                    for (int off=1; off<16; off<<=1) {
                        mn0 = fminf(mn0, __shfl_xor(mn0, off));
                        mx0 = fmaxf(mx0, __shfl_xor(mx0, off));
                        mn1 = fminf(mn1, __shfl_xor(mn1, off));
                        mx1 = fmaxf(mx1, __shfl_xor(mx1, off));
                    }
                    float s0 = (mx0 - mn0) / 15.0f; if (s0 == 0.0f) s0 = 1.0f;
                    float s1 = (mx1 - mn1) / 15.0f; if (s1 == 0.0f) s1 = 1.0f;
                    #pragma unroll
                    for (int j=0;j<4;j++) {
                        float q0 = rintf(fminf(fmaxf((y[j]  -mn0)/s0, 0.0f), 15.0f));
                        float q1 = rintf(fminf(fmaxf((y[j+4]-mn1)/s1, 0.0f), 15.0f));
                        Cb[(size_t)row*N + n0 + j*16     + l15] = f2bf(q0*s0 + mn0);
                        Cb[(size_t)row*N + n0 + (j+4)*16 + l15] = f2bf(q1*s1 + mn1);
                    }
                }
            }
        }
    }
}

// ---------------- causal GQA flash attention, swapped-QK^T ----------------------
// 4 waves (256 thr), QBLK=64; block does qblk pair (qpair, 31-qpair) -> 33 tiles
// each = perfectly uniform 512 blocks; 48KB LDS -> 3 blocks/CU (12 waves/CU).
// Swapped scores: S^T = mfma(K, Q) -> lane holds ONE q row. In-register P
// (cvt_pk + bpermute), no lsP. K single-buffer gll; V double-buffer reg-transpose.
__device__ __forceinline__ int vswz(int d) { return ((d ^ (d >> 3)) & 7) << 4; }

__global__ __launch_bounds__(256) void attn_kernel(
    const unsigned short* __restrict__ Qb,   // [NTOK][NH*HD], pre-scaled (log2e/sqrt(D))
    const unsigned short* __restrict__ Kb,   // [NTOK][NKV*HD]
    const unsigned short* __restrict__ Vb,
    unsigned short* __restrict__ Ob)         // [NTOK][NH*HD]
{
    __shared__ unsigned short lsK[64*128];    // [kv][d-chunks], slot c8' holds chunk c8'^(r&7)
    __shared__ unsigned short lsV[2][128*64]; // [d][kv], elem kv at (kv ^ (sw(d)<<3))

    int tid = threadIdx.x, lane = tid & 63, wv = tid >> 6;   // wv 0..3
    int bidx  = blockIdx.x;
    int bh    = bidx & 31;
    int qpair = bidx >> 5;                     // 0..15
    int h     = bh & 15;
    int b     = bh >> 4;
    int hk    = h >> 2;
    size_t tokbase = (size_t)b * S_;
    int l15 = lane & 15;
    int g   = lane >> 4;
    int prow0 = g << 2;

    auto stageK = [&](int t) {
        #pragma unroll
        for (int it=0; it<4; it++) {
            int mI = it*4 + wv;
            int r  = mI*4 + (lane>>4);
            int c8 = (lane & 15) ^ (r & 7);
            gload_lds16(Kb + ((tokbase + t*64 + r)*NKV_ + hk)*HD_ + (c8<<3), &lsK[mI*512]);
        }
    };
    auto loadV = [&](int t, uint4* vr) {
        #pragma unroll
        for (int it=0; it<4; it++) {
            int idx2 = it*4 + wv;
            int kvchunk = idx2 & 7, dhalf = idx2 >> 3;
            int e = lane & 7, gg = lane >> 3;
            vr[it] = *(const uint4*)(Vb +
                ((tokbase + t*64 + kvchunk*8 + e)*NKV_ + hk)*HD_ + dhalf*64 + gg*8);
        }
    };
    auto writeV = [&](uint4* vr, unsigned short* dstV) {
        #pragma unroll
        for (int it=0; it<4; it++) {
            int idx2 = it*4 + wv;
            int kvchunk = idx2 & 7, dhalf = idx2 >> 3;
            int e = lane & 7, gg = lane >> 3;
            uint4 w = vr[it];
            {   // step 4: 2-dword block swap
                unsigned int s0 = (e&4) ? w.x : w.z;
                unsigned int s1 = (e&4) ? w.y : w.w;
                unsigned int r0 = __shfl_xor(s0, 4);
                unsigned int r1 = __shfl_xor(s1, 4);
                if (e&4) { w.x = r0; w.y = r1; } else { w.z = r0; w.w = r1; }
            }
            {   // step 2: dword-level swap
                unsigned int s0 = (e&2) ? w.x : w.y;
                unsigned int s1 = (e&2) ? w.z : w.w;
                unsigned int r0 = __shfl_xor(s0, 2);
                unsigned int r1 = __shfl_xor(s1, 2);
                if (e&2) { w.x = r0; w.z = r1; } else { w.y = r0; w.w = r1; }
            }
            {   // step 1: u16-within-dword swap
                unsigned int r0 = __shfl_xor(w.x, 1);
                unsigned int r1 = __shfl_xor(w.y, 1);
                unsigned int r2 = __shfl_xor(w.z, 1);
                unsigned int r3 = __shfl_xor(w.w, 1);
                if (e&1) {
                    w.x = (w.x & 0xFFFF0000u) | (r0 >> 16);
                    w.y = (w.y & 0xFFFF0000u) | (r1 >> 16);
                    w.z = (w.z & 0xFFFF0000u) | (r2 >> 16);
                    w.w = (w.w & 0xFFFF0000u) | (r3 >> 16);
                } else {
                    w.x = (w.x & 0x0000FFFFu) | (r0 << 16);
                    w.y = (w.y & 0x0000FFFFu) | (r1 << 16);
                    w.z = (w.z & 0x0000FFFFu) | (r2 << 16);
                    w.w = (w.w & 0x0000FFFFu) | (r3 << 16);
                }
            }
            int d = dhalf*64 + gg*8 + e;
            int sw = (d ^ (d>>3)) & 7;
            int kvx = (kvchunk*8) ^ (sw<<3);
            *(uint4*)(dstV + d*64 + kvx) = w;
        }
    };

    for (int pi = 0; pi < 2; ++pi) {
        int qblk = pi ? (31 - qpair) : qpair;
        int q0   = qblk*64 + wv*16;
        int qlane = q0 + l15;                  // this lane's q row (swapped layout)

        s8v qf[4];
        {
            const unsigned short* qp = Qb + ((tokbase + qlane)*NH_ + h)*HD_ + (g<<3);
            #pragma unroll
            for (int kc=0; kc<4; kc++) qf[kc] = *(const s8v*)(qp + kc*32);
        }

        f32x4 o[8];
        #pragma unroll
        for (int i=0;i<8;i++) o[i] = (f32x4)0.0f;
        float m = -INFINITY, l = 0.0f;         // per-lane (one q row)

        int nt_end = qblk + 1;

        uint4 vr[4];
        loadV(0, vr);                 // loads first (oldest in vm queue)
        stageK(0);                    // gll after -> writeV wait leaves it in flight
        writeV(vr, &lsV[0][0]);
        __syncthreads();              // drains gll: lsK/lsV[0] ready

        for (int t=0; t<nt_end; t++) {
            int cur = t & 1;
            bool more = (t+1 < nt_end);                // block-uniform
            bool fullmask = (q0 + 15) < t*64;          // wave-uniform: tile fully masked
            bool needmask = (t*64 + 63) > q0;          // wave-uniform: diagonal region

            // ---- scores (swapped): S^T = K(64x128) @ Q^T -> lane q = qlane ----
            f32x4 s[4];
            if (!fullmask) {
                __builtin_amdgcn_s_setprio(1);
                #pragma unroll
                for (int nt=0; nt<4; nt++) {
                    s[nt] = (f32x4)0.0f;
                    int row = nt*16 + l15;
                    #pragma unroll
                    for (int kc=0; kc<4; kc++) {
                        int byt = (kc*64 + (g<<4)) ^ ((row & 7) << 4);
                        s8v kfrag = *(const s8v*)&lsK[row*128 + (byt >> 1)];
                        s[nt] = __builtin_amdgcn_mfma_f32_16x16x32_bf16(kfrag, qf[kc], s[nt], 0,0,0);
                    }
                }
                __builtin_amdgcn_s_setprio(0);
            }
            if (more) {
                __syncthreads();       // bar1: all QK reads of lsK done (vm queue empty)
                loadV(t+1, vr);        // issue next V loads (regs)
                stageK(t+1);           // issue next K gll into lsK
            }
            s8v pa[2];
            if (!fullmask) {
                // ---- causal mask + online softmax (exp2), per-lane scalar state ----
                float mt = -INFINITY;
                if (needmask) {
                    #pragma unroll
                    for (int nt=0; nt<4; nt++)
                        #pragma unroll
                        for (int r=0;r<4;r++) {
                            int kvg = t*64 + nt*16 + (g<<2) + r;
                            float sv = s[nt][r];
                            if (kvg > qlane) sv = -1e30f;
                            s[nt][r] = sv;
                            mt = fmaxf(mt, sv);
                        }
                } else {
                    #pragma unroll
                    for (int nt=0; nt<4; nt++)
                        #pragma unroll
                        for (int r=0;r<4;r++) mt = fmaxf(mt, s[nt][r]);
                }
                mt = fmaxf(mt, __shfl_xor(mt, 16));
                mt = fmaxf(mt, __shfl_xor(mt, 32));
                // defer-max (T13): skip rescale if growth <= 8 (values <= 2^8)
                bool rescale = !__all(mt - m <= 8.0f);
                if (rescale) {
                    float mn = fmaxf(m, mt);
                    float scl = fexp2(m - mn);     // m=-inf first tile -> 0
                    m = mn;
                    l *= scl;
                    #pragma unroll
                    for (int r=0;r<4;r++) {
                        float sr = __shfl(scl, (prow0 + r) + (lane & 48));
                        #pragma unroll
                        for (int dt=0; dt<8; dt++) o[dt][r] *= sr;
                    }
                }
                float p[4][4];
                float rs = 0.0f;
                #pragma unroll
                for (int nt=0; nt<4; nt++)
                    #pragma unroll
                    for (int r=0;r<4;r++) {
                        p[nt][r] = fexp2(s[nt][r] - m);
                        rs += p[nt][r];
                    }
                rs += __shfl_xor(rs, 16);
                rs += __shfl_xor(rs, 32);
                l += rs;
                // ---- in-register P -> A-frag (cvt_pk + bpermute); no LDS ----
                unsigned int wpk[4][2];
                #pragma unroll
                for (int nt=0; nt<4; nt++)
                    #pragma unroll
                    for (int pr=0; pr<2; pr++) {
                        unsigned int w_;
                        asm("v_cvt_pk_bf16_f32 %0, %1, %2"
                            : "=v"(w_) : "v"(p[nt][2*pr]), "v"(p[nt][2*pr+1]));
                        wpk[nt][pr] = w_;
                    }
                #pragma unroll
                for (int c=0;c<2;c++) {
                    unsigned int dw[4];
                    #pragma unroll
                    for (int i=0;i<4;i++) {
                        int srcl = l15 + 16*(2*(g&1) + (i>>1));
                        unsigned int a0 = (unsigned int)__shfl((int)wpk[2*c+0][i&1], srcl);
                        unsigned int a1 = (unsigned int)__shfl((int)wpk[2*c+1][i&1], srcl);
                        dw[i] = (g>>1) ? a1 : a0;
                    }
                    uint4 t4; t4.x = dw[0]; t4.y = dw[1]; t4.z = dw[2]; t4.w = dw[3];
                    pa[c] = __builtin_bit_cast(s8v, t4);
                }
            }
            if (more) writeV(vr, &lsV[cur^1][0]);   // waits only V loads (gll in flight)
            if (!fullmask) {
                // ---- PV: O += P(16x64) @ V(64x128) ----
                __builtin_amdgcn_s_setprio(1);
                #pragma unroll
                for (int dt=0; dt<8; dt++) {
                    int row = dt*16 + l15;
                    #pragma unroll
                    for (int c=0;c<2;c++) {
                        int byt = (c*64 + (g<<4)) ^ vswz(row);
                        s8v vfrag = *(const s8v*)&lsV[cur][row*64 + (byt >> 1)];
                        o[dt] = __builtin_amdgcn_mfma_f32_16x16x32_bf16(pa[c], vfrag, o[dt], 0,0,0);
                    }
                }
                __builtin_amdgcn_s_setprio(0);
            }
            __syncthreads();           // bar2: drains gll; publishes lsK(t+1), lsV[cur^1]
        }
        // ---- epilogue: redistribute per-q l across lane groups ----
        #pragma unroll
        for (int r=0;r<4;r++) {
            float lr = __shfl(l, (prow0 + r) + (lane & 48));
            float inv = 1.0f / lr;
            int rq = q0 + prow0 + r;
            #pragma unroll
            for (int dt=0; dt<8; dt++) {
                int d = dt*16 + l15;
                Ob[((tokbase + rq)*NH_ + h)*HD_ + d] = f2bf(o[dt][r] * inv);
            }
        }
    }
}

// ---------------- host launcher --------------------------------------------------
extern "C" void kernel_launch(void* const* d_in, const int* in_sizes, int n_in,
                              void* d_out, int out_size, void* d_ws, size_t ws_size,
                              hipStream_t stream) {
    const float* hs  = (const float*)d_in[0];
    const float* w_q = (const float*)d_in[1];
    const float* b_q = (const float*)d_in[2];
    const float* w_k = (const float*)d_in[3];
    const float* b_k = (const float*)d_in[4];
    const float* w_v = (const float*)d_in[5];
    const float* b_v = (const float*)d_in[6];
    const float* w_o = (const float*)d_in[7];
    float* out = (float*)d_out;

    char* p = (char*)d_ws;
    auto alloc = [&](size_t bytes) { char* r = p; p += (bytes + 255) & ~(size_t)255; return r; };
    unsigned short* hid_h = (unsigned short*)alloc((size_t)NTOK*HID_*2);
    unsigned short* hid_l = (unsigned short*)alloc((size_t)NTOK*HID_*2);
    unsigned short* wq_h  = (unsigned short*)alloc((size_t)NH_*HD_*HID_*2);
    unsigned short* wk_h  = (unsigned short*)alloc((size_t)NKV_*HD_*HID_*2);
    unsigned short* wk_l  = (unsigned short*)alloc((size_t)NKV_*HD_*HID_*2);
    unsigned short* wv_h  = (unsigned short*)alloc((size_t)NKV_*HD_*HID_*2);
    unsigned short* wv_l  = (unsigned short*)alloc((size_t)NKV_*HD_*HID_*2);
    unsigned short* wo_h  = (unsigned short*)alloc((size_t)HID_*NH_*HD_*2);
    unsigned short* qb = (unsigned short*)alloc((size_t)NTOK*NH_*HD_*2);
    unsigned short* kb = (unsigned short*)alloc((size_t)NTOK*NKV_*HD_*2);
    unsigned short* vb = (unsigned short*)alloc((size_t)NTOK*NKV_*HD_*2);
    unsigned short* ao = (unsigned short*)alloc((size_t)NTOK*NH_*HD_*2);
    float* ctab = (float*)alloc((size_t)S_*64*4);
    float* stab = (float*)alloc((size_t)S_*64*4);

    // all fp32 -> bf16 conversions (1 launch)
    {
        int n8 = NTOK*HID_/8 + NH_*HD_*HID_/8 + 2*(NKV_*HD_*HID_/8) + HID_*NH_*HD_/8;
        conv_all<<<(n8 + 255)/256, 256, 0, stream>>>(
            hs, w_q, w_k, w_v, w_o, hid_h, hid_l, wq_h, wk_h, wk_l, wv_h, wv_l, wo_h);
    }
    rope_table<<<(S_*64 + 255)/256, 256, 0, stream>>>(ctab, stab);

    // Q projection + fused RoPE + scale -> qb bf16 (1-pass, NW=4)
    gemm_mp<4,false,false,1><<<(NTOK/128)*(HID_/128), 256, 0, stream>>>(
        hid_h, nullptr, wq_h, nullptr, nullptr, nullptr, b_q, nullptr,
        nullptr, qb, nullptr, ctab, stab, NTOK, NH_*HD_, HID_);

    // K+V projections (fused along N, 3-pass split) + fused RoPE(K)+quant -> kb/vb
    gemm_mp<8,true,true,2><<<(NTOK/128)*2*((NKV_*HD_)/128), 512, 0, stream>>>(
        hid_h, hid_l, wk_h, wk_l, wv_h, wv_l, b_k, b_v,
        nullptr, kb, vb, ctab, stab, NTOK, NKV_*HD_, HID_);

    // causal GQA attention: 512 uniform blocks x 4 waves, QBLK=64 pairs, 48KB LDS
    attn_kernel<<<B_*NH_*16, 256, 0, stream>>>(qb, kb, vb, ao);

    // output projection (no bias), 1-pass bf16 -> fp32 d_out
    gemm_mp<4,false,false,0><<<(NTOK/128)*(HID_/128), 256, 0, stream>>>(
        ao, nullptr, wo_h, nullptr, nullptr, nullptr, nullptr, nullptr,
        out, nullptr, nullptr, nullptr, nullptr, NTOK, HID_, HID_);
}